// Round 1
// baseline (496.783 us; speedup 1.0000x reference)
//
#include <hip/hip_runtime.h>
#include <cstdint>
#include <cstddef>

#define NE 8
#define HD 2048
#define IN 1408
#define NT 2048
#define NP (NT*2)
#define MAXMT 40

typedef __bf16 bf16;
typedef __bf16 bf16x8 __attribute__((ext_vector_type(8)));
typedef __bf16 bf16x4 __attribute__((ext_vector_type(4)));
typedef float f32x4 __attribute__((ext_vector_type(4)));

__device__ __forceinline__ void load_lds16(const void* g, void* l) {
  __builtin_amdgcn_global_load_lds((const __attribute__((address_space(1))) uint32_t*)g,
                                   (__attribute__((address_space(3))) uint32_t*)l, 16, 0, 0);
}

// one wait+barrier per K-step; raw barrier so prefetched loads issued NEXT
// iteration are not drained by compiler-inserted vmcnt(0) at __syncthreads.
#define PIPE_BAR() do { \
    asm volatile("s_waitcnt vmcnt(0) lgkmcnt(0)" ::: "memory"); \
    __builtin_amdgcn_s_barrier(); \
    __builtin_amdgcn_sched_barrier(0); \
  } while (0)

// ---------------- hidden f32 -> bf16 ----------------
__global__ void k_cvt(const float* __restrict__ x, bf16* __restrict__ y) {
  int i = blockIdx.x * 256 + threadIdx.x;           // covers NT*HD/4
  f32x4 v = ((const f32x4*)x)[i];
  bf16x4 o;
  o[0] = (bf16)v[0]; o[1] = (bf16)v[1]; o[2] = (bf16)v[2]; o[3] = (bf16)v[3];
  ((bf16x4*)y)[i] = o;
}

// ---------------- routing: bucket pairs by expert ----------------
__global__ void k_route(const int* __restrict__ idx, const float* __restrict__ w,
                        int* __restrict__ perm_tok, float* __restrict__ perm_w,
                        int* __restrict__ slot_of, int* __restrict__ tiles) {
  __shared__ int cnt[NE], off[NE + 1], rk[NE];
  int tid = threadIdx.x;
  if (tid < NE) { cnt[tid] = 0; rk[tid] = 0; }
  __syncthreads();
  for (int a = tid; a < NP; a += 256) atomicAdd(&cnt[idx[a]], 1);
  __syncthreads();
  if (tid == 0) { off[0] = 0; for (int e = 0; e < NE; e++) off[e + 1] = off[e] + cnt[e]; }
  __syncthreads();
  for (int a = tid; a < NP; a += 256) {
    int e = idx[a];
    int p = off[e] + atomicAdd(&rk[e], 1);
    perm_tok[p] = a >> 1;
    perm_w[p] = w[a];
    slot_of[a] = p;
  }
  __syncthreads();
  if (tid == 0) {
    int n = 0;
    for (int e = 0; e < NE; e++)
      for (int r = off[e]; r < off[e + 1]; r += 128) {
        tiles[n] = e; tiles[MAXMT + n] = r; tiles[2 * MAXMT + n] = off[e + 1];
        n++;
      }
    for (int s = n; s < MAXMT; s++) tiles[s] = -1;
  }
}

// ---------------- pipelined 128x128x64 bf16 GEMM body (f32 C out) ----------------
// 2-phase: issue tile k+1 loads (B->regs, A->LDS[nxt] via global_load_lds)
// before MFMA of tile k; cvt+ds_write B after MFMAs; single raw barrier/iter.
template<int KTOT, int NTOT, bool GATHER>
__device__ __forceinline__ void mm_pipe(const bf16* __restrict__ A,
                                        const float* __restrict__ Bsrc,
                                        const int* __restrict__ perm_tok,
                                        int row0, int rowend, int nb,
                                        float* __restrict__ C) {
  __shared__ __align__(16) bf16 As[2][128 * 64];
  __shared__ __align__(16) bf16 Bs[2][128 * 64];

  int tid = threadIdx.x;
  int lane = tid & 63, wave = tid >> 6;
  int wm = (wave >> 1) * 64, wn = (wave & 1) * 64;

  // A staging: linear LDS dest (global_load_lds requirement), swizzle applied
  // on the global source side (chunk col c XOR row) — m173 pattern.
  const bf16* aG[4]; int aOff[4];
#pragma unroll
  for (int i2 = 0; i2 < 4; i2++) {
    int s = i2 * 256 + tid;
    int r = s >> 3, c = (s & 7) ^ (r & 7);
    int tr = row0 + r; if (tr > NP - 1) tr = NP - 1;
    int arow = GATHER ? perm_tok[tr] : tr;
    aG[i2] = A + (size_t)arow * KTOT + c * 8;
    aOff[i2] = s * 8;
  }
  // B staging: thread owns k-rows kk..kk+7, n-cols nn..nn+3 (transpose to n-major)
  int kk = (tid & 7) * 8, nn = (tid >> 3) * 4;
  const float* gB = Bsrc + (size_t)kk * NTOT + (nb + nn);
  int bslot[4];
#pragma unroll
  for (int i2 = 0; i2 < 4; i2++) { int n = nn + i2; bslot[i2] = (n * 8 + ((tid & 7) ^ (n & 7))) * 8; }

  f32x4 acc[4][4] = {};
  f32x4 v[8];

  // prologue: stage tile 0 (latency exposed once per block)
#pragma unroll
  for (int i2 = 0; i2 < 4; i2++) load_lds16(aG[i2], &As[0][aOff[i2]]);
#pragma unroll
  for (int j = 0; j < 8; j++) v[j] = *(const f32x4*)(gB + (size_t)j * NTOT);
#pragma unroll
  for (int i2 = 0; i2 < 4; i2++) {
    bf16x8 o;
#pragma unroll
    for (int j = 0; j < 8; j++) o[j] = (bf16)v[j][i2];
    *(bf16x8*)(&Bs[0][bslot[i2]]) = o;
  }
  PIPE_BAR();

  const int NK = KTOT / 64;
  int cur = 0;
#pragma unroll 2
  for (int k = 0; k < NK; k++) {
    if (k + 1 < NK) {
      int k0n = (k + 1) * 64;
      // issue next-tile loads: B -> regs (in flight across MFMA phase),
      // A -> LDS[nxt] (async, drained at PIPE_BAR after MFMAs)
#pragma unroll
      for (int j = 0; j < 8; j++) v[j] = *(const f32x4*)(gB + (size_t)(k0n + j) * NTOT);
#pragma unroll
      for (int i2 = 0; i2 < 4; i2++) load_lds16(aG[i2] + k0n, &As[cur ^ 1][aOff[i2]]);
    }
    // compute on buffer cur
#pragma unroll
    for (int ks = 0; ks < 2; ks++) {
      int ckf = ks * 4 + (lane >> 4);
      bf16x8 af[4], bfr[4];
#pragma unroll
      for (int fm = 0; fm < 4; fm++) {
        int m = wm + fm * 16 + (lane & 15);
        af[fm] = *(const bf16x8*)(&As[cur][(m * 8 + (ckf ^ (m & 7))) * 8]);
      }
#pragma unroll
      for (int fn = 0; fn < 4; fn++) {
        int n = wn + fn * 16 + (lane & 15);
        bfr[fn] = *(const bf16x8*)(&Bs[cur][(n * 8 + (ckf ^ (n & 7))) * 8]);
      }
      __builtin_amdgcn_s_setprio(1);
#pragma unroll
      for (int fm = 0; fm < 4; fm++)
#pragma unroll
        for (int fn = 0; fn < 4; fn++)
          acc[fm][fn] = __builtin_amdgcn_mfma_f32_16x16x32_bf16(af[fm], bfr[fn], acc[fm][fn], 0, 0, 0);
      __builtin_amdgcn_s_setprio(0);
    }
    if (k + 1 < NK) {
      // convert + write next B tile into the other buffer (WAR-safe: dbuf)
#pragma unroll
      for (int i2 = 0; i2 < 4; i2++) {
        bf16x8 o;
#pragma unroll
        for (int j = 0; j < 8; j++) o[j] = (bf16)v[j][i2];
        *(bf16x8*)(&Bs[cur ^ 1][bslot[i2]]) = o;
      }
    }
    PIPE_BAR();
    cur ^= 1;
  }

  // epilogue: plain f32 store
#pragma unroll
  for (int fm = 0; fm < 4; fm++) {
#pragma unroll
    for (int rr = 0; rr < 4; rr++) {
      int m = wm + fm * 16 + ((lane >> 4) << 2) + rr;
      int row = row0 + m;
      if (row < rowend) {
#pragma unroll
        for (int fn = 0; fn < 4; fn++) {
          int n = nb + wn + fn * 16 + (lane & 15);
          C[(size_t)row * NTOT + n] = acc[fm][fn][rr];
        }
      }
    }
  }
}

// ---------------- GEMM1: g = X@Gw, u = X@Uw (one dispatch, two halves) ----------------
__launch_bounds__(256, 2)
__global__ void k_mm1(const bf16* __restrict__ hid, const float* __restrict__ gw,
                      const float* __restrict__ uw, const int* __restrict__ perm_tok,
                      const int* __restrict__ tiles,
                      float* __restrict__ g, float* __restrict__ u) {
  int b = blockIdx.x;
  int half = b >= 440 ? 1 : 0;
  int b2 = b - half * 440;
  int slot = b2 / 11, nt = b2 % 11;         // consecutive blocks share A rows
  int e = tiles[slot];
  if (e < 0) return;
  int row0 = tiles[MAXMT + slot], rowend = tiles[2 * MAXMT + slot];
  const float* B = (half ? uw : gw) + (size_t)e * HD * IN;
  float* C = half ? u : g;
  mm_pipe<HD, IN, true>(hid, B, perm_tok, row0, rowend, nt * 128, C);
}

// ---------------- act = silu(g) * u * pair_w  (bf16) ----------------
__global__ void k_act(const float* __restrict__ g, const float* __restrict__ u,
                      const float* __restrict__ pw, bf16* __restrict__ act) {
  int i = blockIdx.x * 256 + threadIdx.x;   // 8 elems/thread, covers NP*IN/8
  int row = i / (IN / 8);
  float w = pw[row];
  f32x4 g0 = ((const f32x4*)g)[2 * i], g1 = ((const f32x4*)g)[2 * i + 1];
  f32x4 u0 = ((const f32x4*)u)[2 * i], u1 = ((const f32x4*)u)[2 * i + 1];
  bf16x8 o;
#pragma unroll
  for (int j = 0; j < 4; j++) {
    float s = g0[j] / (1.0f + __expf(-g0[j]));
    o[j] = (bf16)(s * u0[j] * w);
  }
#pragma unroll
  for (int j = 0; j < 4; j++) {
    float s = g1[j] / (1.0f + __expf(-g1[j]));
    o[4 + j] = (bf16)(s * u1[j] * w);
  }
  ((bf16x8*)act)[i] = o;
}

// ---------------- GEMM2: pout = act @ Dw[e]  (f32 out) ----------------
__launch_bounds__(256, 2)
__global__ void k_mm2(const bf16* __restrict__ act, const float* __restrict__ dw,
                      const int* __restrict__ tiles, float* __restrict__ pout) {
  int b = blockIdx.x;
  int slot = b >> 4, nt = b & 15;
  int e = tiles[slot];
  if (e < 0) return;
  int row0 = tiles[MAXMT + slot], rowend = tiles[2 * MAXMT + slot];
  mm_pipe<IN, HD, false>(act, dw + (size_t)e * IN * HD, nullptr, row0, rowend, nt * 128, pout);
}

// ---------------- combine: out[t] = pout[slot0] + pout[slot1] ----------------
__global__ void k_comb(const float* __restrict__ pout, const int* __restrict__ slot_of,
                       float* __restrict__ out) {
  int i = blockIdx.x * 256 + threadIdx.x;   // covers NT*HD/4
  int t = i >> 9;                            // HD/4 = 512 float4 per row
  int hc = i & 511;
  f32x4 a = ((const f32x4*)(pout + (size_t)slot_of[2 * t] * HD))[hc];
  f32x4 c = ((const f32x4*)(pout + (size_t)slot_of[2 * t + 1] * HD))[hc];
  ((f32x4*)(out + (size_t)t * HD))[hc] = a + c;
}

extern "C" void kernel_launch(void* const* d_in, const int* in_sizes, int n_in,
                              void* d_out, int out_size, void* d_ws, size_t ws_size,
                              hipStream_t stream) {
  const float* hidden  = (const float*)d_in[0];
  const int*   tk_idx  = (const int*)d_in[1];
  const float* tk_w    = (const float*)d_in[2];
  const float* gw      = (const float*)d_in[3];
  const float* uw      = (const float*)d_in[4];
  const float* dw      = (const float*)d_in[5];
  float* out = (float*)d_out;

  char* ws = (char*)d_ws;
  int*   perm_tok = (int*)ws;                               // 16 KB
  float* perm_w   = (float*)(ws + 16384);                   // 16 KB
  int*   slot_of  = (int*)(ws + 32768);                     // 16 KB
  int*   tiles    = (int*)(ws + 49152);                     // ~0.5 KB (reserve 4 KB)
  bf16*  hid_bf   = (bf16*)(ws + 53248);                    // 8 MB
  bf16*  act      = (bf16*)(ws + 53248 + 8388608);          // 11.5 MB
  char*  xbase    = ws + 53248 + 8388608 + 11534336;
  float* gbuf     = (float*)xbase;                          // 23.07 MB (dead after k_act)
  float* ubuf     = (float*)(xbase + 23068672);             // 23.07 MB (dead after k_act)
  float* pout     = (float*)xbase;                          // 33.5 MB, overlays g/u

  k_cvt  <<<4096, 256, 0, stream>>>(hidden, hid_bf);
  k_route<<<1,    256, 0, stream>>>(tk_idx, tk_w, perm_tok, perm_w, slot_of, tiles);
  k_mm1  <<<880,  256, 0, stream>>>(hid_bf, gw, uw, perm_tok, tiles, gbuf, ubuf);
  k_act  <<<2816, 256, 0, stream>>>(gbuf, ubuf, perm_w, act);
  k_mm2  <<<640,  256, 0, stream>>>(act, dw, tiles, pout);
  k_comb <<<4096, 256, 0, stream>>>(pout, slot_of, out);
}

// Round 2
// 479.884 us; speedup vs baseline: 1.0352x; 1.0352x over previous
//
#include <hip/hip_runtime.h>
#include <cstdint>
#include <cstddef>

#define NE 8
#define HD 2048
#define IN 1408
#define NT 2048
#define NP (NT*2)
#define MAXMT 40

typedef __bf16 bf16;
typedef __bf16 bf16x8 __attribute__((ext_vector_type(8)));
typedef __bf16 bf16x4 __attribute__((ext_vector_type(4)));
typedef float f32x4 __attribute__((ext_vector_type(4)));

__device__ __forceinline__ void load_lds16(const void* g, void* l) {
  __builtin_amdgcn_global_load_lds((const __attribute__((address_space(1))) uint32_t*)g,
                                   (__attribute__((address_space(3))) uint32_t*)l, 16, 0, 0);
}

// ---------------- hidden f32 -> bf16 ----------------
__global__ void k_cvt(const float* __restrict__ x, bf16* __restrict__ y) {
  int i = blockIdx.x * 256 + threadIdx.x;           // covers NT*HD/4
  f32x4 v = ((const f32x4*)x)[i];
  bf16x4 o;
  o[0] = (bf16)v[0]; o[1] = (bf16)v[1]; o[2] = (bf16)v[2]; o[3] = (bf16)v[3];
  ((bf16x4*)y)[i] = o;
}

// ---------------- routing: bucket pairs by expert + build L2-friendly block maps ----------------
__global__ void k_route(const int* __restrict__ idx, const float* __restrict__ w,
                        int* __restrict__ perm_tok, float* __restrict__ perm_w,
                        int* __restrict__ slot_of, int* __restrict__ tiles,
                        int* __restrict__ bmap1, int* __restrict__ bmap2) {
  __shared__ int cnt[NE], off[NE + 1], rk[NE], sb[NE + 1];
  int tid = threadIdx.x;
  if (tid < NE) { cnt[tid] = 0; rk[tid] = 0; }
  __syncthreads();
  for (int a = tid; a < NP; a += 256) atomicAdd(&cnt[idx[a]], 1);
  __syncthreads();
  if (tid == 0) { off[0] = 0; for (int e = 0; e < NE; e++) off[e + 1] = off[e] + cnt[e]; }
  __syncthreads();
  for (int a = tid; a < NP; a += 256) {
    int e = idx[a];
    int p = off[e] + atomicAdd(&rk[e], 1);
    perm_tok[p] = a >> 1;
    perm_w[p] = w[a];
    slot_of[a] = p;
  }
  __syncthreads();
  if (tid == 0) {
    int n = 0;
    for (int e = 0; e < NE; e++)
      for (int r = off[e]; r < off[e + 1]; r += 128) {
        tiles[n] = e; tiles[MAXMT + n] = r; tiles[2 * MAXMT + n] = off[e + 1];
        n++;
      }
    for (int s = n; s < MAXMT; s++) tiles[s] = -1;
    tiles[3 * MAXMT] = n;
    int a = 0;
    for (int e = 0; e < NE; e++) { sb[e] = a; a += (cnt[e] + 127) >> 7; }
    sb[NE] = a;
  }
  __syncthreads();
  // block maps: expert-major, nt-major, slot-minor -> same-(e,nt) blocks adjacent
  if (tid < NE) {
    int e = tid, s0 = sb[e], s1 = sb[e + 1];
    int j1 = s0 * 11, j2 = s0 * 16;
    for (int nt = 0; nt < 11; nt++)
      for (int s = s0; s < s1; s++) bmap1[j1++] = s | (nt << 16);
    for (int nt = 0; nt < 16; nt++)
      for (int s = s0; s < s1; s++) bmap2[j2++] = s | (nt << 16);
  }
}

// ---------------- deep-pipelined 128x128x64 bf16 GEMM body (f32 C out) ----------------
// A: 2-buf LDS via global_load_lds, issued 1 tile ahead, drained with vmcnt(8)
// B: f32->reg 2 tiles ahead, cvt+ds_write 1 tile ahead => loads get >1 full
//    iteration to land; vmcnt never drains to 0 in the main loop (T4).
#define MM_COMPUTE(kk) do { \
    const bf16* Ab_ = As + ((kk) & 1) * (128 * 64); \
    const bf16* Bb_ = Bs + ((kk) & 1) * (128 * 64); \
    _Pragma("unroll") \
    for (int ks = 0; ks < 2; ks++) { \
      int ckf = ks * 4 + (lane >> 4); \
      bf16x8 af[4], bfr[4]; \
      _Pragma("unroll") \
      for (int fm = 0; fm < 4; fm++) { \
        int m_ = wm + fm * 16 + (lane & 15); \
        af[fm] = *(const bf16x8*)(Ab_ + (m_ * 8 + (ckf ^ (m_ & 7))) * 8); \
      } \
      _Pragma("unroll") \
      for (int fn = 0; fn < 4; fn++) { \
        int n_ = wn + fn * 16 + (lane & 15); \
        bfr[fn] = *(const bf16x8*)(Bb_ + (n_ * 8 + (ckf ^ (n_ & 7))) * 8); \
      } \
      __builtin_amdgcn_s_setprio(1); \
      _Pragma("unroll") \
      for (int fm = 0; fm < 4; fm++) \
        _Pragma("unroll") \
        for (int fn = 0; fn < 4; fn++) \
          acc[fm][fn] = __builtin_amdgcn_mfma_f32_16x16x32_bf16(af[fm], bfr[fn], acc[fm][fn], 0, 0, 0); \
      __builtin_amdgcn_s_setprio(0); \
    } \
  } while (0)

// body for kk <= NK-2: gload A(kk+1) [pinned first so vmcnt(8) drains it],
// load B(kk+2) -> vLoad, MFMA(kk), cvt vCon=B(kk+1) -> LDS, counted wait+barrier
#define MM_BODY(kk, vCon, vLoad, WSTR) do { \
    { int k0a = ((kk) + 1) * 64; \
      bf16* dA_ = As + (((kk) + 1) & 1) * (128 * 64); \
      _Pragma("unroll") \
      for (int i2 = 0; i2 < 4; i2++) load_lds16(aG[i2] + k0a, dA_ + aOff[i2]); } \
    __builtin_amdgcn_sched_barrier(0); \
    if ((kk) + 2 < NK) { int k0b = ((kk) + 2) * 64; \
      _Pragma("unroll") \
      for (int j = 0; j < 8; j++) vLoad[j] = *(const f32x4*)(gB + (size_t)(k0b + j) * NTOT); } \
    MM_COMPUTE(kk); \
    { bf16* Bw_ = Bs + (((kk) + 1) & 1) * (128 * 64); \
      _Pragma("unroll") \
      for (int i2 = 0; i2 < 4; i2++) { bf16x8 o; \
        _Pragma("unroll") for (int j = 0; j < 8; j++) o[j] = (bf16)vCon[j][i2]; \
        *(bf16x8*)(Bw_ + bslot[i2]) = o; } } \
    asm volatile("s_waitcnt " WSTR ::: "memory"); \
    __builtin_amdgcn_s_barrier(); \
    __builtin_amdgcn_sched_barrier(0); \
  } while (0)

template<int KTOT, int NTOT, bool GATHER>
__device__ __forceinline__ void mm_pipe(const bf16* __restrict__ A,
                                        const float* __restrict__ Bsrc,
                                        const int* __restrict__ perm_tok,
                                        int row0, int rowend, int nb,
                                        float* __restrict__ C) {
  constexpr int NK = KTOT / 64;           // 32 (mm1) or 22 (mm2), both even
  __shared__ __align__(16) bf16 As[2 * 128 * 64];
  __shared__ __align__(16) bf16 Bs[2 * 128 * 64];

  int tid = threadIdx.x;
  int lane = tid & 63, wave = tid >> 6;
  int wm = (wave >> 1) * 64, wn = (wave & 1) * 64;

  // A staging: linear LDS dest, swizzle on the global source side (m173)
  const bf16* aG[4]; int aOff[4];
#pragma unroll
  for (int i2 = 0; i2 < 4; i2++) {
    int s = i2 * 256 + tid;
    int r = s >> 3, c = (s & 7) ^ (r & 7);
    int tr = row0 + r; if (tr > NP - 1) tr = NP - 1;
    int arow = GATHER ? perm_tok[tr] : tr;
    aG[i2] = A + (size_t)arow * KTOT + c * 8;
    aOff[i2] = s * 8;
  }
  // B staging: thread owns k-rows kk0..kk0+7, n-cols nn..nn+3 (transpose to n-major)
  int kk0 = (tid & 7) * 8, nn = (tid >> 3) * 4;
  const float* gB = Bsrc + (size_t)kk0 * NTOT + (nb + nn);
  int bslot[4];
#pragma unroll
  for (int i2 = 0; i2 < 4; i2++) { int n = nn + i2; bslot[i2] = (n * 8 + ((tid & 7) ^ (n & 7))) * 8; }

  f32x4 acc[4][4] = {};
  f32x4 vA[8], vB[8];

  // ---- prologue: A(0)->LDS, B(0)->vA, B(1)->vB, cvt B(0)->Bs[0] ----
#pragma unroll
  for (int i2 = 0; i2 < 4; i2++) load_lds16(aG[i2], As + aOff[i2]);
  __builtin_amdgcn_sched_barrier(0);
#pragma unroll
  for (int j = 0; j < 8; j++) vA[j] = *(const f32x4*)(gB + (size_t)j * NTOT);
#pragma unroll
  for (int j = 0; j < 8; j++) vB[j] = *(const f32x4*)(gB + (size_t)(64 + j) * NTOT);
#pragma unroll
  for (int i2 = 0; i2 < 4; i2++) {
    bf16x8 o;
#pragma unroll
    for (int j = 0; j < 8; j++) o[j] = (bf16)vA[j][i2];
    *(bf16x8*)(Bs + bslot[i2]) = o;
  }
  asm volatile("s_waitcnt vmcnt(8) lgkmcnt(0)" ::: "memory");  // A(0),B(0) done; B(1) in flight
  __builtin_amdgcn_s_barrier();
  __builtin_amdgcn_sched_barrier(0);

  // ---- main loop: bodies kk=0..NK-3 with counted vmcnt; peel NK-2 (drain), NK-1 (compute only) ----
#pragma unroll 1
  for (int k = 0; k + 2 < NK; k += 2) {
    MM_BODY(k,     vB, vA, "vmcnt(8) lgkmcnt(0)");
    MM_BODY(k + 1, vA, vB, "vmcnt(8) lgkmcnt(0)");
  }
  MM_BODY(NK - 2, vB, vA, "vmcnt(0) lgkmcnt(0)");   // NK even => cons is vB here
  MM_COMPUTE(NK - 1);

  // epilogue: plain f32 store
#pragma unroll
  for (int fm = 0; fm < 4; fm++) {
#pragma unroll
    for (int rr = 0; rr < 4; rr++) {
      int m = wm + fm * 16 + ((lane >> 4) << 2) + rr;
      int row = row0 + m;
      if (row < rowend) {
#pragma unroll
        for (int fn = 0; fn < 4; fn++) {
          int n = nb + wn + fn * 16 + (lane & 15);
          C[(size_t)row * NTOT + n] = acc[fm][fn][rr];
        }
      }
    }
  }
}

// m204 bijective chunked-XCD swizzle over W valid blocks; returns logical id or -1
__device__ __forceinline__ int xcd_logical(int b, int W) {
  int xcd = b & 7, p = b >> 3;
  int q = W >> 3, r = W & 7;
  int cs = xcd < r ? q + 1 : q;
  if (p >= cs) return -1;
  return (xcd < r ? xcd * (q + 1) : r * (q + 1) + (xcd - r) * q) + p;
}

// ---------------- GEMM1: g = X@Gw, u = X@Uw ----------------
__launch_bounds__(256, 2)
__global__ void k_mm1(const bf16* __restrict__ hid, const float* __restrict__ gw,
                      const float* __restrict__ uw, const int* __restrict__ perm_tok,
                      const int* __restrict__ tiles, const int* __restrict__ bmap1,
                      float* __restrict__ g, float* __restrict__ u) {
  int nsl = tiles[3 * MAXMT];
  int hn = 11 * nsl;
  int l = xcd_logical(blockIdx.x, 2 * hn);
  if (l < 0) return;
  int half = l >= hn ? 1 : 0;
  int m = bmap1[l - half * hn];
  int slot = m & 0xffff, nt = m >> 16;
  int e = tiles[slot];
  int row0 = tiles[MAXMT + slot], rowend = tiles[2 * MAXMT + slot];
  const float* B = (half ? uw : gw) + (size_t)e * HD * IN;
  float* C = half ? u : g;
  mm_pipe<HD, IN, true>(hid, B, perm_tok, row0, rowend, nt * 128, C);
}

// ---------------- act = silu(g) * u * pair_w  (bf16) ----------------
__global__ void k_act(const float* __restrict__ g, const float* __restrict__ u,
                      const float* __restrict__ pw, bf16* __restrict__ act) {
  int i = blockIdx.x * 256 + threadIdx.x;   // 8 elems/thread, covers NP*IN/8
  int row = i / (IN / 8);
  float w = pw[row];
  f32x4 g0 = ((const f32x4*)g)[2 * i], g1 = ((const f32x4*)g)[2 * i + 1];
  f32x4 u0 = ((const f32x4*)u)[2 * i], u1 = ((const f32x4*)u)[2 * i + 1];
  bf16x8 o;
#pragma unroll
  for (int j = 0; j < 4; j++) {
    float s = g0[j] / (1.0f + __expf(-g0[j]));
    o[j] = (bf16)(s * u0[j] * w);
  }
#pragma unroll
  for (int j = 0; j < 4; j++) {
    float s = g1[j] / (1.0f + __expf(-g1[j]));
    o[4 + j] = (bf16)(s * u1[j] * w);
  }
  ((bf16x8*)act)[i] = o;
}

// ---------------- GEMM2: pout = act @ Dw[e]  (f32 out) ----------------
__launch_bounds__(256, 2)
__global__ void k_mm2(const bf16* __restrict__ act, const float* __restrict__ dw,
                      const int* __restrict__ tiles, const int* __restrict__ bmap2,
                      float* __restrict__ pout) {
  int nsl = tiles[3 * MAXMT];
  int l = xcd_logical(blockIdx.x, 16 * nsl);
  if (l < 0) return;
  int m = bmap2[l];
  int slot = m & 0xffff, nt = m >> 16;
  int e = tiles[slot];
  int row0 = tiles[MAXMT + slot], rowend = tiles[2 * MAXMT + slot];
  mm_pipe<IN, HD, false>(act, dw + (size_t)e * IN * HD, nullptr, row0, rowend, nt * 128, pout);
}

// ---------------- combine: out[t] = pout[slot0] + pout[slot1] ----------------
__global__ void k_comb(const float* __restrict__ pout, const int* __restrict__ slot_of,
                       float* __restrict__ out) {
  int i = blockIdx.x * 256 + threadIdx.x;   // covers NT*HD/4
  int t = i >> 9;                            // HD/4 = 512 float4 per row
  int hc = i & 511;
  f32x4 a = ((const f32x4*)(pout + (size_t)slot_of[2 * t] * HD))[hc];
  f32x4 c = ((const f32x4*)(pout + (size_t)slot_of[2 * t + 1] * HD))[hc];
  ((f32x4*)(out + (size_t)t * HD))[hc] = a + c;
}

extern "C" void kernel_launch(void* const* d_in, const int* in_sizes, int n_in,
                              void* d_out, int out_size, void* d_ws, size_t ws_size,
                              hipStream_t stream) {
  const float* hidden  = (const float*)d_in[0];
  const int*   tk_idx  = (const int*)d_in[1];
  const float* tk_w    = (const float*)d_in[2];
  const float* gw      = (const float*)d_in[3];
  const float* uw      = (const float*)d_in[4];
  const float* dw      = (const float*)d_in[5];
  float* out = (float*)d_out;

  char* ws = (char*)d_ws;
  int*   perm_tok = (int*)ws;                               // 16 KB
  float* perm_w   = (float*)(ws + 16384);                   // 16 KB
  int*   slot_of  = (int*)(ws + 32768);                     // 16 KB
  int*   tiles    = (int*)(ws + 49152);                     // 121 ints (reserve 1 KB)
  int*   bmap1    = (int*)(ws + 50176);                     // <=440 ints (reserve 2 KB)
  int*   bmap2    = (int*)(ws + 52224);                     // <=640 ints (reserve 3 KB)
  bf16*  hid_bf   = (bf16*)(ws + 65536);                    // 8 MB
  bf16*  act      = (bf16*)(ws + 65536 + 8388608);          // 11.5 MB
  char*  xbase    = ws + 65536 + 8388608 + 11534336;
  float* gbuf     = (float*)xbase;                          // 23.07 MB (dead after k_act)
  float* ubuf     = (float*)(xbase + 23068672);             // 23.07 MB (dead after k_act)
  float* pout     = (float*)xbase;                          // 33.5 MB, overlays g/u

  k_cvt  <<<4096, 256, 0, stream>>>(hidden, hid_bf);
  k_route<<<1,    256, 0, stream>>>(tk_idx, tk_w, perm_tok, perm_w, slot_of, tiles, bmap1, bmap2);
  k_mm1  <<<880,  256, 0, stream>>>(hid_bf, gw, uw, perm_tok, tiles, bmap1, gbuf, ubuf);
  k_act  <<<2816, 256, 0, stream>>>(gbuf, ubuf, perm_w, act);
  k_mm2  <<<640,  256, 0, stream>>>(act, dw, tiles, bmap2, pout);
  k_comb <<<4096, 256, 0, stream>>>(pout, slot_of, out);
}

// Round 3
// 467.834 us; speedup vs baseline: 1.0619x; 1.0258x over previous
//
#include <hip/hip_runtime.h>
#include <cstdint>
#include <cstddef>

#define NE 8
#define HD 2048
#define IN 1408
#define NT 2048
#define NP (NT*2)
#define MAXMT 40

typedef __bf16 bf16;
typedef __bf16 bf16x8 __attribute__((ext_vector_type(8)));
typedef __bf16 bf16x4 __attribute__((ext_vector_type(4)));
typedef float f32x4 __attribute__((ext_vector_type(4)));

__device__ __forceinline__ void load_lds16(const void* g, void* l) {
  __builtin_amdgcn_global_load_lds((const __attribute__((address_space(1))) uint32_t*)g,
                                   (__attribute__((address_space(3))) uint32_t*)l, 16, 0, 0);
}

// ---------------- hidden f32 -> bf16 ----------------
__global__ void k_cvt(const float* __restrict__ x, bf16* __restrict__ y) {
  int i = blockIdx.x * 256 + threadIdx.x;           // covers NT*HD/4
  f32x4 v = ((const f32x4*)x)[i];
  bf16x4 o;
  o[0] = (bf16)v[0]; o[1] = (bf16)v[1]; o[2] = (bf16)v[2]; o[3] = (bf16)v[3];
  ((bf16x4*)y)[i] = o;
}

// ---------------- weight transpose+convert: [K][N] f32 -> [N][K] bf16 ----------------
// tile 128(K) x 64(N) per block via padded LDS; reads/writes coalesced.
template<int K, int N>
__global__ void k_cvtw(const float* __restrict__ src, bf16* __restrict__ dst) {
  constexpr int KT = K / 128, NT2 = N / 64;
  int b = blockIdx.x;
  int e = b / (KT * NT2), rem = b % (KT * NT2);
  int kt = rem / NT2, ntl = rem % NT2;
  const float* S = src + (size_t)e * K * N + (size_t)kt * 128 * N + ntl * 64;
  bf16* D = dst + (size_t)e * N * K + (size_t)ntl * 64 * K + kt * 128;
  __shared__ __align__(16) float T[128 * 68];       // pitch 68 keeps 16B-aligned f32x4 stores
  int tid = threadIdx.x;
#pragma unroll
  for (int p = 0; p < 8; p++) {                     // read 128 x 64 f32, coalesced
    int r = p * 16 + (tid >> 4), c4 = (tid & 15) * 4;
    *(f32x4*)(T + r * 68 + c4) = *(const f32x4*)(S + (size_t)r * N + c4);
  }
  __syncthreads();
  int n = tid >> 2;                                 // write 64 n-rows x 128 k bf16
#pragma unroll
  for (int p = 0; p < 4; p++) {
    int k0 = (p * 4 + (tid & 3)) * 8;
    bf16x8 o;
#pragma unroll
    for (int j = 0; j < 8; j++) o[j] = (bf16)T[(k0 + j) * 68 + n];
    *(bf16x8*)(D + (size_t)n * K + k0) = o;
  }
}

// ---------------- routing: bucket pairs by expert + build L2-friendly block maps ----------------
__global__ void k_route(const int* __restrict__ idx, const float* __restrict__ w,
                        int* __restrict__ perm_tok, float* __restrict__ perm_w,
                        int* __restrict__ slot_of, int* __restrict__ tiles,
                        int* __restrict__ bmap1, int* __restrict__ bmap2) {
  __shared__ int cnt[NE], off[NE + 1], rk[NE], sb[NE + 1];
  int tid = threadIdx.x;
  if (tid < NE) { cnt[tid] = 0; rk[tid] = 0; }
  __syncthreads();
  for (int a = tid; a < NP; a += 256) atomicAdd(&cnt[idx[a]], 1);
  __syncthreads();
  if (tid == 0) { off[0] = 0; for (int e = 0; e < NE; e++) off[e + 1] = off[e] + cnt[e]; }
  __syncthreads();
  for (int a = tid; a < NP; a += 256) {
    int e = idx[a];
    int p = off[e] + atomicAdd(&rk[e], 1);
    perm_tok[p] = a >> 1;
    perm_w[p] = w[a];
    slot_of[a] = p;
  }
  __syncthreads();
  if (tid == 0) {
    int n = 0;
    for (int e = 0; e < NE; e++)
      for (int r = off[e]; r < off[e + 1]; r += 128) {
        tiles[n] = e; tiles[MAXMT + n] = r; tiles[2 * MAXMT + n] = off[e + 1];
        n++;
      }
    for (int s = n; s < MAXMT; s++) tiles[s] = -1;
    tiles[3 * MAXMT] = n;
    int a = 0;
    for (int e = 0; e < NE; e++) { sb[e] = a; a += (cnt[e] + 127) >> 7; }
    sb[NE] = a;
  }
  __syncthreads();
  // block maps: expert-major, nt-major, slot-minor -> same-(e,nt) blocks adjacent
  if (tid < NE) {
    int e = tid, s0 = sb[e], s1 = sb[e + 1];
    int j1 = s0 * 11, j2 = s0 * 16;
    for (int nt = 0; nt < 11; nt++)
      for (int s = s0; s < s1; s++) bmap1[j1++] = s | (nt << 16);
    for (int nt = 0; nt < 16; nt++)
      for (int s = s0; s < s1; s++) bmap2[j2++] = s | (nt << 16);
  }
}

// ---------------- m97-structure 128x128x64 bf16 GEMM core (f32 C out) ----------------
// Both operands staged via global_load_lds(16B) with source-side XOR swizzle;
// single-buffered 32KB LDS, 2-barrier K-loop (hardware-verified structure, 912 TF ref).
template<int KTOT, int NTOT, bool GATHER>
__device__ __forceinline__ void mm_core(const bf16* __restrict__ A,
                                        const bf16* __restrict__ WT,   // [n][KTOT] bf16
                                        const int* __restrict__ perm_tok,
                                        int row0, int rowend, int nb,
                                        float* __restrict__ C) {
  __shared__ __align__(16) bf16 As[128 * 64];
  __shared__ __align__(16) bf16 Bs[128 * 64];

  int tid = threadIdx.x;
  int lane = tid & 63, wave = tid >> 6;
  int wm = (wave >> 1) * 64, wn = (wave & 1) * 64;

  // staging: slot s -> row r=s>>3, swizzled chunk col c=(s&7)^(r&7); LDS linear (m173)
  const bf16* aG[4]; const bf16* bG[4]; int sOff[4];
#pragma unroll
  for (int i2 = 0; i2 < 4; i2++) {
    int s = i2 * 256 + tid;
    int r = s >> 3, c = (s & 7) ^ (r & 7);
    int tr = row0 + r; if (tr > NP - 1) tr = NP - 1;
    int arow = GATHER ? perm_tok[tr] : tr;
    aG[i2] = A + (size_t)arow * KTOT + c * 8;
    bG[i2] = WT + (size_t)(nb + r) * KTOT + c * 8;
    sOff[i2] = s * 8;
  }

  f32x4 acc[4][4] = {};

  for (int k0 = 0; k0 < KTOT; k0 += 64) {
    __syncthreads();
#pragma unroll
    for (int i2 = 0; i2 < 4; i2++) load_lds16(aG[i2] + k0, As + sOff[i2]);
#pragma unroll
    for (int i2 = 0; i2 < 4; i2++) load_lds16(bG[i2] + k0, Bs + sOff[i2]);
    __syncthreads();
#pragma unroll
    for (int ks = 0; ks < 2; ks++) {
      int ckf = ks * 4 + (lane >> 4);
      bf16x8 af[4], bfr[4];
#pragma unroll
      for (int fm = 0; fm < 4; fm++) {
        int m_ = wm + fm * 16 + (lane & 15);
        af[fm] = *(const bf16x8*)(As + (m_ * 8 + (ckf ^ (m_ & 7))) * 8);
      }
#pragma unroll
      for (int fn = 0; fn < 4; fn++) {
        int n_ = wn + fn * 16 + (lane & 15);
        bfr[fn] = *(const bf16x8*)(Bs + (n_ * 8 + (ckf ^ (n_ & 7))) * 8);
      }
#pragma unroll
      for (int fm = 0; fm < 4; fm++)
#pragma unroll
        for (int fn = 0; fn < 4; fn++)
          acc[fm][fn] = __builtin_amdgcn_mfma_f32_16x16x32_bf16(af[fm], bfr[fn], acc[fm][fn], 0, 0, 0);
    }
  }

  // epilogue: plain f32 store
#pragma unroll
  for (int fm = 0; fm < 4; fm++) {
#pragma unroll
    for (int rr = 0; rr < 4; rr++) {
      int m = wm + fm * 16 + ((lane >> 4) << 2) + rr;
      int row = row0 + m;
      if (row < rowend) {
#pragma unroll
        for (int fn = 0; fn < 4; fn++) {
          int n = nb + wn + fn * 16 + (lane & 15);
          C[(size_t)row * NTOT + n] = acc[fm][fn][rr];
        }
      }
    }
  }
}

// m204 bijective chunked-XCD swizzle over W valid blocks; returns logical id or -1
__device__ __forceinline__ int xcd_logical(int b, int W) {
  int xcd = b & 7, p = b >> 3;
  int q = W >> 3, r = W & 7;
  int cs = xcd < r ? q + 1 : q;
  if (p >= cs) return -1;
  return (xcd < r ? xcd * (q + 1) : r * (q + 1) + (xcd - r) * q) + p;
}

// ---------------- GEMM1: g = X@Gw, u = X@Uw (bf16 transposed weights) ----------------
__launch_bounds__(256, 2)
__global__ void k_mm1(const bf16* __restrict__ hid, const bf16* __restrict__ gwt,
                      const bf16* __restrict__ uwt, const int* __restrict__ perm_tok,
                      const int* __restrict__ tiles, const int* __restrict__ bmap1,
                      float* __restrict__ g, float* __restrict__ u, int halfsel) {
  int nsl = tiles[3 * MAXMT];
  int hn = 11 * nsl;
  int W = (halfsel < 0) ? 2 * hn : hn;
  int l = xcd_logical(blockIdx.x, W);
  if (l < 0) return;
  int half = (halfsel < 0) ? (l >= hn ? 1 : 0) : halfsel;
  int li = (halfsel < 0) ? (l - (l >= hn ? hn : 0)) : l;
  int m = bmap1[li];
  int slot = m & 0xffff, nt = m >> 16;
  int e = tiles[slot];
  int row0 = tiles[MAXMT + slot], rowend = tiles[2 * MAXMT + slot];
  const bf16* WTp = (half ? uwt : gwt) + (size_t)e * IN * HD;
  mm_core<HD, IN, true>(hid, WTp, perm_tok, row0, rowend, nt * 128, half ? u : g);
}

// ---------------- act = silu(g) * u * pair_w  (bf16) ----------------
__global__ void k_act(const float* __restrict__ g, const float* __restrict__ u,
                      const float* __restrict__ pw, bf16* __restrict__ act) {
  int i = blockIdx.x * 256 + threadIdx.x;   // 8 elems/thread, covers NP*IN/8
  int row = i / (IN / 8);
  float w = pw[row];
  f32x4 g0 = ((const f32x4*)g)[2 * i], g1 = ((const f32x4*)g)[2 * i + 1];
  f32x4 u0 = ((const f32x4*)u)[2 * i], u1 = ((const f32x4*)u)[2 * i + 1];
  bf16x8 o;
#pragma unroll
  for (int j = 0; j < 4; j++) {
    float s = g0[j] / (1.0f + __expf(-g0[j]));
    o[j] = (bf16)(s * u0[j] * w);
  }
#pragma unroll
  for (int j = 0; j < 4; j++) {
    float s = g1[j] / (1.0f + __expf(-g1[j]));
    o[4 + j] = (bf16)(s * u1[j] * w);
  }
  ((bf16x8*)act)[i] = o;
}

// ---------------- GEMM2: pout = act @ Dw[e]  (f32 out) ----------------
__launch_bounds__(256, 2)
__global__ void k_mm2(const bf16* __restrict__ act, const bf16* __restrict__ dwt,
                      const int* __restrict__ tiles, const int* __restrict__ bmap2,
                      float* __restrict__ pout) {
  int nsl = tiles[3 * MAXMT];
  int l = xcd_logical(blockIdx.x, 16 * nsl);
  if (l < 0) return;
  int m = bmap2[l];
  int slot = m & 0xffff, nt = m >> 16;
  int e = tiles[slot];
  int row0 = tiles[MAXMT + slot], rowend = tiles[2 * MAXMT + slot];
  mm_core<IN, HD, false>(act, dwt + (size_t)e * HD * IN, nullptr, row0, rowend, nt * 128, pout);
}

// ---------------- combine: out[t] = pout[slot0] + pout[slot1] ----------------
__global__ void k_comb(const float* __restrict__ pout, const int* __restrict__ slot_of,
                       float* __restrict__ out) {
  int i = blockIdx.x * 256 + threadIdx.x;   // covers NT*HD/4
  int t = i >> 9;                            // HD/4 = 512 float4 per row
  int hc = i & 511;
  f32x4 a = ((const f32x4*)(pout + (size_t)slot_of[2 * t] * HD))[hc];
  f32x4 c = ((const f32x4*)(pout + (size_t)slot_of[2 * t + 1] * HD))[hc];
  ((f32x4*)(out + (size_t)t * HD))[hc] = a + c;
}

extern "C" void kernel_launch(void* const* d_in, const int* in_sizes, int n_in,
                              void* d_out, int out_size, void* d_ws, size_t ws_size,
                              hipStream_t stream) {
  const float* hidden  = (const float*)d_in[0];
  const int*   tk_idx  = (const int*)d_in[1];
  const float* tk_w    = (const float*)d_in[2];
  const float* gw      = (const float*)d_in[3];
  const float* uw      = (const float*)d_in[4];
  const float* dw      = (const float*)d_in[5];
  float* out = (float*)d_out;

  char* ws = (char*)d_ws;
  int*   perm_tok = (int*)ws;                               // 16 KB
  float* perm_w   = (float*)(ws + 16384);                   // 16 KB
  int*   slot_of  = (int*)(ws + 32768);                     // 16 KB
  int*   tiles    = (int*)(ws + 49152);                     // 121 ints (1 KB)
  int*   bmap1    = (int*)(ws + 50176);                     // <=440 ints (2 KB)
  int*   bmap2    = (int*)(ws + 52224);                     // <=640 ints (3 KB)

  const size_t base   = 65536;
  const size_t sz_hid = 8388608;        // NT*HD*2
  const size_t sz_act = 11534336;       // NP*IN*2
  const size_t sz_wt  = 46137344;       // 8*IN*HD*2 (same for all three matrices)
  const size_t sz_g   = 23068672;       // NP*IN*4

  bf16* hid_bf = (bf16*)(ws + base);
  bf16* act    = (bf16*)(ws + base + sz_hid);
  char* wbase  = ws + base + sz_hid + sz_act;

  bool wide = ws_size >= base + sz_hid + sz_act + 3 * sz_wt + 2 * sz_g;

  k_cvt  <<<4096, 256, 0, stream>>>(hidden, hid_bf);
  k_route<<<1,    256, 0, stream>>>(tk_idx, tk_w, perm_tok, perm_w, slot_of, tiles, bmap1, bmap2);

  if (wide) {
    bf16* gwt = (bf16*)wbase;
    bf16* uwt = (bf16*)(wbase + sz_wt);
    bf16* dwt = (bf16*)(wbase + 2 * sz_wt);
    float* g  = (float*)(wbase + 3 * sz_wt);
    float* u  = (float*)(wbase + 3 * sz_wt + sz_g);
    float* pout = (float*)wbase;        // overlays gwt/uwt (dead after k_mm1)

    k_cvtw<HD, IN><<<2816, 256, 0, stream>>>(gw, gwt);
    k_cvtw<HD, IN><<<2816, 256, 0, stream>>>(uw, uwt);
    k_cvtw<IN, HD><<<2816, 256, 0, stream>>>(dw, dwt);
    k_mm1 <<<880,  256, 0, stream>>>(hid_bf, gwt, uwt, perm_tok, tiles, bmap1, g, u, -1);
    k_act <<<2816, 256, 0, stream>>>(g, u, perm_w, act);
    k_mm2 <<<640,  256, 0, stream>>>(act, dwt, tiles, bmap2, pout);
    k_comb<<<4096, 256, 0, stream>>>(pout, slot_of, out);
  } else {
    bf16* wt  = (bf16*)wbase;           // single reused weight buffer
    float* g  = (float*)(wbase + sz_wt);
    float* u  = (float*)(wbase + sz_wt + sz_g);
    float* pout = (float*)(wbase + sz_wt);  // overlays g/u (dead after k_act)

    k_cvtw<HD, IN><<<2816, 256, 0, stream>>>(gw, wt);
    k_mm1 <<<448,  256, 0, stream>>>(hid_bf, wt, wt, perm_tok, tiles, bmap1, g, u, 0);
    k_cvtw<HD, IN><<<2816, 256, 0, stream>>>(uw, wt);
    k_mm1 <<<448,  256, 0, stream>>>(hid_bf, wt, wt, perm_tok, tiles, bmap1, g, u, 1);
    k_act <<<2816, 256, 0, stream>>>(g, u, perm_w, act);
    k_cvtw<IN, HD><<<2816, 256, 0, stream>>>(dw, wt);
    k_mm2 <<<640,  256, 0, stream>>>(act, wt, tiles, bmap2, pout);
    k_comb<<<4096, 256, 0, stream>>>(pout, slot_of, out);
  }
}